// Round 17
// baseline (595.878 us; speedup 1.0000x reference)
//
#include <hip/hip_runtime.h>
#include <hip/hip_bf16.h>
#include <hip/hip_fp8.h>
#include <stdint.h>

#define B_ 32
#define T_ 12
#define N_ 1024
#define D_ 64
#define F_ 16
#define KH_ 8
#define BT_ (B_*T_)
#define NROWS_ (BT_*N_)
#define K3_ 3072

typedef unsigned short u16;
typedef unsigned char u8;
struct __align__(8) u16x4 { u16 x, y, z, w; };
struct __align__(16) u16x8 { u16 v[8]; };
typedef __attribute__((ext_vector_type(8))) short short8v;
typedef __attribute__((ext_vector_type(4))) float f32x4;
typedef __attribute__((ext_vector_type(2))) long long2v;

__device__ __forceinline__ float b2f(u16 u) {
  union { float f; unsigned int i; } c; c.i = ((unsigned int)u) << 16; return c.f;
}
__device__ __forceinline__ u16 f2b(float f) {
  union { float f; unsigned int i; } c; c.f = f;
  unsigned int u = c.i;
  unsigned int r = ((u >> 16) & 1u) + 0x7FFFu;
  return (u16)((u + r) >> 16);
}
__device__ __forceinline__ u8 f2e4(float f) {
  __hip_fp8_e4m3 h(f);
  return (u8)h.__x;
}
__device__ __forceinline__ unsigned cvt_pk_bf16(float lo, float hi) {
  unsigned r;
  asm volatile("v_cvt_pk_bf16_f32 %0, %1, %2" : "=v"(r) : "v"(lo), "v"(hi));
  return r;
}
// k-interleave perm: logical k-group g (0..7) within a 64-byte block -> byte (g&3)*16+(g>>2)*8
__device__ __forceinline__ int kperm(int c) {
  int g = (c >> 3) & 7, e = c & 7;
  return (c & ~63) | ((g & 3) << 4) | ((g >> 2) << 3) | e;
}

__device__ __forceinline__ void gload_lds16(const void* g, void* l) {
  __builtin_amdgcn_global_load_lds(
      (const __attribute__((address_space(1))) unsigned int*)g,
      (__attribute__((address_space(3))) unsigned int*)l, 16, 0, 0);
}

// ---- K0 (merged): fe = relu(feat@W) (+ transposed K copies) | adj copy (fp8 x256, k-perm) | weight transposes.
__global__ __launch_bounds__(256) void k_pre(
    const float* __restrict__ feat0, const float* __restrict__ feat1,
    const float* __restrict__ Wq0, const float* __restrict__ Wk0,
    const float* __restrict__ Wq1, const float* __restrict__ Wk1,
    const float* __restrict__ adj,
    const float* __restrict__ Wq, const float* __restrict__ Wk,
    const float* __restrict__ Wv,
    const float* __restrict__ Wx1, const float* __restrict__ Wx2,
    const float* __restrict__ Ws, const float* __restrict__ Wt,
    const float* __restrict__ Wh1, const float* __restrict__ Wh2,
    const float* __restrict__ Wgcn,
    float* __restrict__ fe, float* __restrict__ feKt, u8* __restrict__ Acat8,
    u16* __restrict__ Wqkvt, u16* __restrict__ W1t, u16* __restrict__ W2t,
    u16* __restrict__ Wstt, u16* __restrict__ Wh1t, u16* __restrict__ Wh2t,
    u16* __restrict__ Wgcnt)
{
  int bid = blockIdx.x;
  int t = threadIdx.x;
  if (bid < 1024) {
    int r = bid;
    int m = t >> 6, d = t & 63;
    const float* feat = (m < 2) ? feat0 : feat1;
    const float* W = (m == 0) ? Wq0 : (m == 1) ? Wk0 : (m == 2) ? Wq1 : Wk1;
    float acc = 0.f;
    #pragma unroll
    for (int ff = 0; ff < F_; ++ff) acc += feat[r*F_ + ff] * W[ff*D_ + d];
    float val = fmaxf(acc, 0.f);
    fe[((size_t)m*N_ + r)*D_ + d] = val;
    if (m & 1) {
      int g = m >> 1;
      feKt[((size_t)g*D_ + d)*N_ + r] = val;
    }
  } else if (bid < 2048) {
    int r = bid - 1024;
    for (int c = t; c < N_; c += 256)
      Acat8[(size_t)r*K3_ + kperm(c)] = f2e4(adj[(size_t)r*N_ + c] * 256.0f);
  } else {
    int g0 = (bid - 2048)*256 + t;
    const int stride = 64*256;
    for (int i = g0; i < 192*128; i += stride) {
      int nn = i >> 7, kk = i & 127;
      const float* W = (nn < 64) ? Wq : (nn < 128) ? Wk : Wv;
      Wqkvt[i] = f2b(W[kk*64 + (nn & 63)]);
    }
    for (int i = g0; i < 64*64; i += stride) {
      int nn = i >> 6, kk = i & 63;
      W1t[i] = f2b(Wx1[kk*64 + nn]);
      W2t[i] = f2b(Wx2[kk*64 + nn]);
      Wh1t[i] = f2b(Wh1[kk*64 + nn]);
      Wh2t[i] = f2b(Wh2[kk*64 + nn]);
    }
    for (int i = g0; i < 64*128; i += stride) {
      int nn = i >> 7, kk = i & 127;
      Wstt[i] = f2b((kk < 64) ? Ws[kk*64 + nn] : Wt[(kk-64)*64 + nn]);
    }
    for (int i = g0; i < 256*64; i += stride) {
      int cc = i >> 6, kk = i & 63;
      Wgcnt[i] = f2b(Wgcn[(size_t)((cc >> 6)*64 + kk)*64 + (cc & 63)]);
    }
  }
}

// ---- K1: S_g = softmax(FEQ @ FEK^T / 8) rows -> Acat8 (fp8, x256, k-perm), coalesced via feKt
__global__ __launch_bounds__(256) void k_graph_softmax(const float* __restrict__ fe,
                                                       const float* __restrict__ feKt,
                                                       u8* __restrict__ Acat8) {
  int r = blockIdx.x, g = blockIdx.y;
  const float* FEQ = fe + (size_t)(g*2 + 0)*N_*D_;
  const float* Kt  = feKt + (size_t)g*D_*N_;
  __shared__ float q[D_];
  __shared__ float red[256];
  int tid = threadIdx.x;
  if (tid < D_) q[tid] = FEQ[(size_t)r*D_ + tid];
  __syncthreads();
  float lg[4] = {0.f, 0.f, 0.f, 0.f};
  for (int f = 0; f < D_; ++f) {
    float qf = q[f];
    const float* kt = Kt + (size_t)f*N_;
    #pragma unroll
    for (int j = 0; j < 4; ++j) lg[j] += qf * kt[tid + j*256];
  }
  float mx = -1e30f;
  #pragma unroll
  for (int j = 0; j < 4; ++j) { lg[j] *= 0.125f; mx = fmaxf(mx, lg[j]); }
  red[tid] = mx; __syncthreads();
  for (int s = 128; s > 0; s >>= 1) { if (tid < s) red[tid] = fmaxf(red[tid], red[tid+s]); __syncthreads(); }
  mx = red[0]; __syncthreads();
  float sum = 0.f;
  #pragma unroll
  for (int j = 0; j < 4; ++j) { lg[j] = __expf(lg[j]-mx); sum += lg[j]; }
  red[tid] = sum; __syncthreads();
  for (int s = 128; s > 0; s >>= 1) { if (tid < s) red[tid] += red[tid+s]; __syncthreads(); }
  float inv = 256.0f / red[0];
  #pragma unroll
  for (int j = 0; j < 4; ++j) {
    int c = tid + j*256;
    Acat8[(size_t)r*K3_ + (1+g)*N_ + kperm(c)] = f2e4(lg[j]*inv);
  }
}

// ---- K2 (MFMA): [BTN,64] @ Wgcnt^T[64,256] -> G0 bf16 row-major + Yt1..3 fp8 transposed (k-perm node axis)
__global__ __launch_bounds__(256) void k_xw_mfma(
    const float* __restrict__ X, const u16* __restrict__ Wgcnt,
    u16* __restrict__ G0, u8* __restrict__ Yt1, u8* __restrict__ Yt2, u8* __restrict__ Yt3)
{
  __shared__ __align__(16) u16 SM[24576];
  u16* Als = SM;
  u16* Bls = SM + 8192;
  u8*  T8  = (u8*)SM;
  u16* Gls = SM;
  int m0 = blockIdx.x * 128;
  int t = threadIdx.x;
  int w = t >> 6, l = t & 63;

  {
    int rsub = l >> 3, pch = l & 7;
    #pragma unroll
    for (int i = 0; i < 8; ++i) {
      int R0 = w*64 + i*8;
      int n = R0 + rsub;
      int q = pch ^ (n & 7);
      gload_lds16(Wgcnt + (size_t)n*64 + q*8, &Bls[R0*64]);
    }
  }
  #pragma unroll
  for (int i = 0; i < 4; ++i) {
    int flat = t + 256*i;
    int row = flat >> 3, c = flat & 7;
    const float* src = X + (size_t)(m0+row)*64 + c*8;
    float4 f0 = *(const float4*)src;
    float4 f1 = *(const float4*)(src + 4);
    u16x8 pk;
    pk.v[0]=f2b(f0.x); pk.v[1]=f2b(f0.y); pk.v[2]=f2b(f0.z); pk.v[3]=f2b(f0.w);
    pk.v[4]=f2b(f1.x); pk.v[5]=f2b(f1.y); pk.v[6]=f2b(f1.z); pk.v[7]=f2b(f1.w);
    int cs = c ^ (row & 7);
    *(u16x8*)&Als[row*64 + cs*8] = pk;
  }
  __syncthreads();

  int wm = w & 1, wn = w >> 1;
  int lr = l & 15, lk = l >> 4;
  f32x4 acc[4][8] = {};
  #pragma unroll
  for (int ks = 0; ks < 2; ++ks) {
    short8v av[4], bv[8];
    #pragma unroll
    for (int fm = 0; fm < 4; ++fm) {
      int r = wm*64 + fm*16 + lr;
      int ch = (ks*4 + lk) ^ (r & 7);
      av[fm] = *(const short8v*)&Als[r*64 + ch*8];
    }
    #pragma unroll
    for (int fn = 0; fn < 8; ++fn) {
      int n = wn*128 + fn*16 + lr;
      int ch = (ks*4 + lk) ^ (n & 7);
      bv[fn] = *(const short8v*)&Bls[n*64 + ch*8];
    }
    #pragma unroll
    for (int fm = 0; fm < 4; ++fm)
      #pragma unroll
      for (int fn = 0; fn < 8; ++fn)
        acc[fm][fn] = __builtin_amdgcn_mfma_f32_16x16x32_bf16(av[fm], bv[fn], acc[fm][fn], 0, 0, 0);
  }
  __syncthreads();

  #pragma unroll
  for (int fm = 0; fm < 4; ++fm) {
    int row0 = wm*64 + fm*16 + lk*4;
    #pragma unroll
    for (int fn = 0; fn < 8; ++fn) {
      int c = wn*128 + fn*16 + lr;
      if (c >= 64) {
        int dp = c - 64;
        unsigned pk = (unsigned)f2e4(acc[fm][fn][0])
                    | ((unsigned)f2e4(acc[fm][fn][1]) << 8)
                    | ((unsigned)f2e4(acc[fm][fn][2]) << 16)
                    | ((unsigned)f2e4(acc[fm][fn][3]) << 24);
        *(unsigned*)&T8[dp*128 + (row0 ^ ((dp & 7) << 3))] = pk;
      }
    }
  }
  __syncthreads();
  {
    int bt = m0 >> 10, nb = m0 & 1023;
    #pragma unroll
    for (int i = 0; i < 12; ++i) {
      int cc = t + 256*i;
      int dp = cc >> 4, nc = cc & 15;
      int n0 = nc*8;
      unsigned long long v8 = *(const unsigned long long*)&T8[dp*128 + (n0 ^ ((dp & 7) << 3))];
      int p = dp >> 6, d = dp & 63;
      u8* Yt = (p == 0) ? Yt1 : (p == 1) ? Yt2 : Yt3;
      int gq = (n0 >> 3) & 7;
      int n0p = (n0 & ~63) | ((gq & 3) << 4) | ((gq >> 2) << 3);
      *(unsigned long long*)&Yt[((size_t)bt*64 + d)*1024 + nb + n0p] = v8;
    }
  }
  __syncthreads();

  if (wn == 0) {
    #pragma unroll
    for (int fm = 0; fm < 4; ++fm) {
      int row0 = wm*64 + fm*16 + lk*4;
      #pragma unroll
      for (int fn = 0; fn < 4; ++fn) {
        int c = fn*16 + lr;
        #pragma unroll
        for (int j = 0; j < 4; ++j) {
          int row = row0 + j;
          Gls[row*64 + (c ^ ((row & 7) << 3))] = f2b(acc[fm][fn][j]);
        }
      }
    }
  }
  __syncthreads();
  #pragma unroll
  for (int i = 0; i < 4; ++i) {
    int cc = t + 256*i;
    int row = cc >> 3, ch = cc & 7;
    u16x8 vv = *(const u16x8*)&Gls[row*64 + ((ch*8) ^ ((row & 7) << 3))];
    *(u16x8*)&G0[(size_t)(m0 + row)*64 + ch*8] = vv;
  }
}

// ---- K3 (MFMA fp8): per bt-pair, C[128,128] = (256*Acat)[128,3072] @ Ystack; HS = relu(C/256 + G0 + b)
// k-interleaved memory: one ds_read_b128 per fragment yields both ks operands (conflict-free).
#define BM 128
#define BK3 64
#define NKT3 (K3_/BK3)   // 48
__global__ __launch_bounds__(256) void k_spatial_mfma(
    const u8* __restrict__ Acat8,
    const u8* __restrict__ Yt1, const u8* __restrict__ Yt2, const u8* __restrict__ Yt3,
    const float* __restrict__ bgcn,
    u16* __restrict__ HS)
{
  __shared__ __align__(16) u8 SM8[32768];
  int f = blockIdx.x + 8*blockIdx.y;
  int u = f & 7, v = f >> 3;
  int btp = u*24 + (v >> 3);
  int m0  = (v & 7) * BM;
  int bt0 = btp * 2;

  int t = threadIdx.x;
  int w = t >> 6, l = t & 63;
  int rsub = l >> 2, pch = l & 3;

  f32x4 acc[4][4] = {};
  int wm = w >> 1, wn = w & 1;
  int lr = l & 15, lk = l >> 4;

  const u8* aSrc[2];
  size_t bOff[2];
  int R0s[2];
  #pragma unroll
  for (int i = 0; i < 2; ++i) {
    int row = w*32 + i*16 + rsub;
    int q = pch ^ ((row >> 1) & 3);
    aSrc[i] = Acat8 + (size_t)(m0 + row)*K3_ + q*16;
    int bt = bt0 + (row >> 6), d = row & 63;
    bOff[i] = ((size_t)bt*64 + d)*1024 + q*16;
    R0s[i] = w*32 + i*16;
  }

  #pragma unroll
  for (int i = 0; i < 2; ++i) {
    gload_lds16(aSrc[i], &SM8[R0s[i]*64]);
    gload_lds16(Yt1 + bOff[i], &SM8[16384 + R0s[i]*64]);
  }
  __syncthreads();

  int buf = 0;
  for (int kt = 0; kt < NKT3; ++kt) {
    if (kt + 1 < NKT3) {
      int k0 = (kt + 1) * BK3;
      int pl = k0 >> 10, kk = k0 & 1023;
      const u8* Yt = (pl == 0) ? Yt1 : (pl == 1) ? Yt2 : Yt3;
      int bo = (buf ^ 1) * 8192;
      #pragma unroll
      for (int i = 0; i < 2; ++i) {
        gload_lds16(aSrc[i] + k0, &SM8[bo + R0s[i]*64]);
        gload_lds16(Yt + bOff[i] + kk, &SM8[16384 + bo + R0s[i]*64]);
      }
    }
    const u8* A8 = SM8 + buf*8192;
    const u8* B8 = SM8 + 16384 + buf*8192;
    long2v av[4], bv[4];
    #pragma unroll
    for (int fm = 0; fm < 4; ++fm) {
      int r = wm*64 + fm*16 + lr;
      int sl = lk ^ ((r >> 1) & 3);
      av[fm] = *(const long2v*)(A8 + r*64 + sl*16);
    }
    #pragma unroll
    for (int fn = 0; fn < 4; ++fn) {
      int n = wn*64 + fn*16 + lr;
      int sl = lk ^ ((n >> 1) & 3);
      bv[fn] = *(const long2v*)(B8 + n*64 + sl*16);
    }
    #pragma unroll
    for (int ks = 0; ks < 2; ++ks)
      #pragma unroll
      for (int fm = 0; fm < 4; ++fm)
        #pragma unroll
        for (int fn = 0; fn < 4; ++fn)
          acc[fm][fn] = __builtin_amdgcn_mfma_f32_16x16x32_fp8_fp8(av[fm][ks], bv[fn][ks], acc[fm][fn], 0, 0, 0);
    __syncthreads();
    buf ^= 1;
  }

  u16* Tls = (u16*)SM8;
  #pragma unroll
  for (int fm = 0; fm < 4; ++fm) {
    #pragma unroll
    for (int fn = 0; fn < 4; ++fn) {
      int col = wn*64 + fn*16 + lr;
      int cc = col >> 3, cw = col & 7;
      #pragma unroll
      for (int j = 0; j < 4; ++j) {
        int node = wm*64 + fm*16 + lk*4 + j;
        int sc = cc ^ (node & 7);
        Tls[node*128 + sc*8 + cw] = f2b(acc[fm][fn][j] * 0.00390625f);
      }
    }
  }
  __syncthreads();
  #pragma unroll
  for (int i = 0; i < 8; ++i) {
    int flat = t + 256*i;
    int node = flat >> 4, cc = flat & 15;
    int sc = cc ^ (node & 7);
    u16x8 zv = *(const u16x8*)&Tls[node*128 + sc*8];
    int bt = bt0 + (cc >> 3), d0 = (cc & 7)*8;
    size_t idx = ((size_t)bt*N_ + (m0 + node))*64 + d0;
    u16x8 gv = *(const u16x8*)&HS[idx];
    float4 b0 = *(const float4*)&bgcn[d0];
    float4 b1 = *(const float4*)&bgcn[d0 + 4];
    float bb[8] = { b0.x, b0.y, b0.z, b0.w, b1.x, b1.y, b1.z, b1.w };
    u16x8 ov;
    #pragma unroll
    for (int e = 0; e < 8; ++e) {
      float vv2 = b2f(zv.v[e]) + b2f(gv.v[e]) + bb[e];
      ov.v[e] = f2b(fmaxf(vv2, 0.f));
    }
    *(u16x8*)&HS[idx] = ov;
  }
}

// ---- K4 (fully fused): QKV projection (per-wave MFMA, B-frags from L2-hot Wqkvt) +
// MFMA attention + HT GEMMs. q/k/v never touch HBM.
__global__ __launch_bounds__(256) void k_attn_ht(
    const float* __restrict__ X, const float* __restrict__ STE,
    const u16* __restrict__ Wqkvt,
    const float* __restrict__ bq, const float* __restrict__ bk, const float* __restrict__ bv,
    const u16* __restrict__ W1t, const u16* __restrict__ W2t,
    const float* __restrict__ bx1, const float* __restrict__ bx2,
    u16* __restrict__ HT)
{
  __shared__ __align__(16) u16 XC[4][16*128];  // 16 KB (zero-padded rows 12..15, chunk-swizzled)
  __shared__ __align__(16) u16 QS[4][12*64];   // 6 KB
  __shared__ __align__(16) u16 KS[4][12*64];   // 6 KB
  __shared__ __align__(16) u16 VT[4][64*24];   // 12 KB
  __shared__ __align__(16) u16 Ols[48*64];     // 6 KB
  __shared__ __align__(16) u16 H1ls[48*64];    // 6 KB
  __shared__ __align__(16) u16 W1ls[64*64];    // 8 KB
  __shared__ __align__(16) u16 W2ls[64*64];    // 8 KB
  int t = threadIdx.x;
  int w = t >> 6, l = t & 63;

  {
    int rsub = l >> 3, pch = l & 7;
    #pragma unroll
    for (int i = 0; i < 2; ++i) {
      int R0 = w*16 + i*8;
      int row = R0 + rsub;
      int sq = pch ^ (row & 7);
      gload_lds16(W1t + (size_t)row*64 + sq*8, &W1ls[R0*64]);
      gload_lds16(W2t + (size_t)row*64 + sq*8, &W2ls[R0*64]);
    }
  }

  int flat = blockIdx.x*4 + w;
  int b = flat >> 10, n = flat & 1023;

  // ---- stage [X|STE] rows (wave-private), bf16, chunk-swizzled; zero-pad rows 12..15
  {
    u16* xc = &XC[w][0];
    int c0 = l, c1 = 64 + l;
    #pragma unroll
    for (int tt = 0; tt < T_; ++tt) {
      size_t rbase = ((size_t)(b*T_ + tt)*N_ + n)*64;
      float xv = X[rbase + l];
      float sv = STE[rbase + l];
      xc[tt*128 + (((c0 >> 3) ^ (tt & 7)) << 3) + (c0 & 7)] = f2b(xv);
      xc[tt*128 + (((c1 >> 3) ^ (tt & 7)) << 3) + (c1 & 7)] = f2b(sv);
    }
    #pragma unroll
    for (int tt = T_; tt < 16; ++tt) {
      xc[tt*128 + (((c0 >> 3) ^ (tt & 7)) << 3) + (c0 & 7)] = 0;
      xc[tt*128 + (((c1 >> 3) ^ (tt & 7)) << 3) + (c1 & 7)] = 0;
    }
  }

  int lr = l & 15, lk = l >> 4;

  // ---- QKV GEMM: rows = t (16, 12 valid), cols 0..191; B-fragments direct from global
  {
    f32x4 accq[12];
    #pragma unroll
    for (int fn = 0; fn < 12; ++fn) accq[fn] = f32x4{0.f, 0.f, 0.f, 0.f};
    #pragma unroll
    for (int ks = 0; ks < 4; ++ks) {
      short8v avx = *(const short8v*)&XC[w][lr*128 + (((ks*4 + lk) ^ (lr & 7)) << 3)];
      #pragma unroll
      for (int fn = 0; fn < 12; ++fn) {
        short8v bvw = *(const short8v*)&Wqkvt[(size_t)(fn*16 + lr)*128 + (ks*4 + lk)*8];
        accq[fn] = __builtin_amdgcn_mfma_f32_16x16x32_bf16(avx, bvw, accq[fn], 0, 0, 0);
      }
    }
    // bias + relu -> scatter into QS/KS/VT (wave-private; sel uniform per fragment)
    #pragma unroll
    for (int fn = 0; fn < 12; ++fn) {
      int sel = fn >> 2;
      int d = (fn & 3)*16 + lr;
      float bias = ((sel == 0) ? bq : (sel == 1) ? bk : bv)[d];
      #pragma unroll
      for (int j = 0; j < 4; ++j) {
        int tt = lk*4 + j;
        if (tt < T_) {
          u16 bv16 = f2b(fmaxf(accq[fn][j] + bias, 0.f));
          if (sel == 0)      QS[w][tt*64 + (((d >> 3) ^ (tt & 7)) << 3) + (d & 7)] = bv16;
          else if (sel == 1) KS[w][tt*64 + (((d >> 3) ^ (tt & 7)) << 3) + (d & 7)] = bv16;
          else               VT[w][d*24 + tt] = bv16;
        }
      }
    }
    #pragma unroll
    for (int tt = T_; tt < 16; ++tt) VT[w][l*24 + tt] = 0;
  }

  // ---- attention (wave-private LDS; compiler inserts lgkmcnt for RAW)
  int g = l >> 4;
  int sr = l & 15;
  short8v z8 = {0,0,0,0,0,0,0,0};
  float scale = 0.3535533906f;

  for (int h = 0; h < KH_; ++h) {
    short8v kf = *(const short8v*)&KS[w][sr*64 + ((h ^ (sr & 7)) << 3)];
    short8v qf = *(const short8v*)&QS[w][sr*64 + ((h ^ (sr & 7)) << 3)];
    short8v avk = (l < 16) ? kf : z8;
    short8v bvq = (l < 16) ? qf : z8;
    f32x4 zc = {0.f, 0.f, 0.f, 0.f};
    f32x4 S = __builtin_amdgcn_mfma_f32_16x16x32_bf16(avk, bvq, zc, 0, 0, 0);
    float sc0 = S[0]*scale, sc1 = S[1]*scale, sc2 = S[2]*scale, sc3 = S[3]*scale;
    bool gv = (g < 3);
    float mown = gv ? fmaxf(fmaxf(sc0, sc1), fmaxf(sc2, sc3)) : -1e30f;
    float m1 = fmaxf(mown, __shfl_xor(mown, 16));
    float m2 = fmaxf(m1, __shfl_xor(m1, 48));
    float e0 = gv ? __expf(sc0 - m2) : 0.f;
    float e1 = gv ? __expf(sc1 - m2) : 0.f;
    float e2 = gv ? __expf(sc2 - m2) : 0.f;
    float e3 = gv ? __expf(sc3 - m2) : 0.f;
    float ss = e0 + e1 + e2 + e3;
    float s1 = ss + __shfl_xor(ss, 16);
    float s2 = s1 + __shfl_xor(s1, 48);
    float rn = 1.0f / s2;
    float p0 = e0*rn, p1 = e1*rn, p2 = e2*rn, p3 = e3*rn;
    float pa0 = __shfl_xor(p0, 16), pa1 = __shfl_xor(p1, 16),
          pa2 = __shfl_xor(p2, 16), pa3 = __shfl_xor(p3, 16);
    float pb0 = __shfl_xor(p0, 48), pb1 = __shfl_xor(p1, 48),
          pb2 = __shfl_xor(p2, 48), pb3 = __shfl_xor(p3, 48);
    float v0, v1, v2, v3, v4, v5, v6, v7;
    if (g == 0)      { v0=p0;  v1=p1;  v2=p2;  v3=p3;  v4=pa0; v5=pa1; v6=pa2; v7=pa3; }
    else if (g == 1) { v0=pb0; v1=pb1; v2=pb2; v3=pb3; v4=0;   v5=0;   v6=0;   v7=0;   }
    else             { v0=0; v1=0; v2=0; v3=0; v4=0; v5=0; v6=0; v7=0; }
    union { unsigned u[4]; short8v s; } pk;
    pk.u[0] = cvt_pk_bf16(v0, v1);
    pk.u[1] = cvt_pk_bf16(v2, v3);
    pk.u[2] = cvt_pk_bf16(v4, v5);
    pk.u[3] = cvt_pk_bf16(v6, v7);
    int vrow = h*8 + (l & 7);
    short8v vf = *(const short8v*)&VT[w][vrow*24 + ((l >> 4) & 1)*8];
    short8v av2 = (g < 2) ? vf : z8;
    f32x4 O = __builtin_amdgcn_mfma_f32_16x16x32_bf16(av2, pk.s, zc, 0, 0, 0);
    if (g < 2 && sr < T_) {
      int r = w*T_ + sr;
      unsigned lo = cvt_pk_bf16(O[0], O[1]);
      unsigned hi = cvt_pk_bf16(O[2], O[3]);
      unsigned off = (unsigned)(r*64 + ((h ^ (r & 7)) << 3) + g*4);
      uint2 pr; pr.x = lo; pr.y = hi;
      *(uint2*)&Ols[off] = pr;
    }
  }
  __syncthreads();

  // ---- GEMM1: H1 = relu(O @ Wx1 + bx1)
  int col = w*16 + lr;
  f32x4 acc1[3] = {};
  #pragma unroll
  for (int ks = 0; ks < 2; ++ks) {
    short8v av[3], bvv;
    #pragma unroll
    for (int fm = 0; fm < 3; ++fm) {
      int r = fm*16 + lr;
      int ch = (ks*4 + lk) ^ (r & 7);
      av[fm] = *(const short8v*)&Ols[r*64 + ch*8];
    }
    {
      int nn = w*16 + lr;
      int ch = (ks*4 + lk) ^ (nn & 7);
      bvv = *(const short8v*)&W1ls[nn*64 + ch*8];
    }
    #pragma unroll
    for (int fm = 0; fm < 3; ++fm)
      acc1[fm] = __builtin_amdgcn_mfma_f32_16x16x32_bf16(av[fm], bvv, acc1[fm], 0, 0, 0);
  }
  {
    float bias1 = bx1[col];
    #pragma unroll
    for (int fm = 0; fm < 3; ++fm)
      #pragma unroll
      for (int j = 0; j < 4; ++j) {
        int r = fm*16 + lk*4 + j;
        H1ls[r*64 + ((col >> 3) ^ (r & 7))*8 + (col & 7)] = f2b(fmaxf(acc1[fm][j] + bias1, 0.f));
      }
  }
  __syncthreads();

  // ---- GEMM2: HT = H1 @ Wx2 + bx2
  f32x4 acc2[3] = {};
  #pragma unroll
  for (int ks = 0; ks < 2; ++ks) {
    short8v av[3], bvv;
    #pragma unroll
    for (int fm = 0; fm < 3; ++fm) {
      int r = fm*16 + lr;
      int ch = (ks*4 + lk) ^ (r & 7);
      av[fm] = *(const short8v*)&H1ls[r*64 + ch*8];
    }
    {
      int nn = w*16 + lr;
      int ch = (ks*4 + lk) ^ (nn & 7);
      bvv = *(const short8v*)&W2ls[nn*64 + ch*8];
    }
    #pragma unroll
    for (int fm = 0; fm < 3; ++fm)
      acc2[fm] = __builtin_amdgcn_mfma_f32_16x16x32_bf16(av[fm], bvv, acc2[fm], 0, 0, 0);
  }
  {
    float bias2 = bx2[col];
    #pragma unroll
    for (int fm = 0; fm < 3; ++fm)
      #pragma unroll
      for (int j = 0; j < 4; ++j) {
        int r = fm*16 + lk*4 + j;
        int fp = blockIdx.x*4 + (r / T_);
        int tt = r % T_;
        int b2 = fp >> 10, n2 = fp & 1023;
        HT[((size_t)(b2*T_ + tt)*N_ + n2)*64 + col] = f2b(acc2[fm][j] + bias2);
      }
  }
}

// ---- K5 (MFMA): gated fusion + output head, 128 rows/block, all-LDS chain
__global__ __launch_bounds__(256) void k_fusion_mfma(
    const float* __restrict__ X,
    const u16* __restrict__ HS, const u16* __restrict__ HT,
    const u16* __restrict__ Wstt, const u16* __restrict__ Wh1t, const u16* __restrict__ Wh2t,
    const float* __restrict__ btb, const float* __restrict__ bh1, const float* __restrict__ bh2,
    float* __restrict__ out)
{
  __shared__ __align__(16) u16 Als[128*128];
  __shared__ __align__(16) u16 Wst[64*128];
  __shared__ __align__(16) u16 W1ls[64*64];
  __shared__ __align__(16) u16 W2ls[64*64];
  __shared__ __align__(16) u16 Hls[128*64];
  int m0 = blockIdx.x * 128;
  int t = threadIdx.x;
  int w = t >> 6, l = t & 63;

  {
    int rsub = l >> 4, pch = l & 15;
    #pragma unroll
    for (int i = 0; i < 8; ++i) {
      int R0 = w*32 + i*4;
      int row = R0 + rsub;
      int q = pch ^ (row & 7);
      const u16* src = (q < 8) ? (HS + (size_t)(m0 + row)*64 + q*8)
                               : (HT + (size_t)(m0 + row)*64 + (q - 8)*8);
      gload_lds16(src, &Als[R0*128]);
    }
    #pragma unroll
    for (int i = 0; i < 4; ++i) {
      int R0 = w*16 + i*4;
      int n = R0 + rsub;
      int q = pch ^ (n & 7);
      gload_lds16(Wstt + (size_t)n*128 + q*8, &Wst[R0*128]);
    }
  }
  {
    int rsub = l >> 3, pch = l & 7;
    #pragma unroll
    for (int i = 0; i < 2; ++i) {
      int R0 = w*16 + i*8;
      int row = R0 + rsub;
      int q = pch ^ (row & 7);
      gload_lds16(Wh1t + (size_t)row*64 + q*8, &W1ls[R0*64]);
      gload_lds16(Wh2t + (size_t)row*64 + q*8, &W2ls[R0*64]);
    }
  }
  __syncthreads();

  int lr = l & 15, lk = l >> 4;
  f32x4 acc1[2][4] = {};
  #pragma unroll
  for (int ks = 0; ks < 4; ++ks) {
    short8v av[2], bvv[4];
    #pragma unroll
    for (int fm = 0; fm < 2; ++fm) {
      int r = w*32 + fm*16 + lr;
      int ch = (ks*4 + lk) ^ (r & 7);
      av[fm] = *(const short8v*)&Als[r*128 + ch*8];
    }
    #pragma unroll
    for (int fn = 0; fn < 4; ++fn) {
      int n = fn*16 + lr;
      int ch = (ks*4 + lk) ^ (n & 7);
      bvv[fn] = *(const short8v*)&Wst[n*128 + ch*8];
    }
    #pragma unroll
    for (int fm = 0; fm < 2; ++fm)
      #pragma unroll
      for (int fn = 0; fn < 4; ++fn)
        acc1[fm][fn] = __builtin_amdgcn_mfma_f32_16x16x32_bf16(av[fm], bvv[fn], acc1[fm][fn], 0, 0, 0);
  }
  #pragma unroll
  for (int fm = 0; fm < 2; ++fm) {
    #pragma unroll
    for (int fn = 0; fn < 4; ++fn) {
      int col = fn*16 + lr;
      float bb = btb[col];
      #pragma unroll
      for (int j = 0; j < 4; ++j) {
        int row = w*32 + fm*16 + lk*4 + j;
        float a_s = acc1[fm][fn][j] + bb;
        float zg = 1.f/(1.f + __expf(-a_s));
        int cs = (col >> 3) ^ (row & 7);
        float hs = b2f(Als[row*128 + cs*8 + (col & 7)]);
        float ht = b2f(Als[row*128 + (cs + 8)*8 + (col & 7)]);
        float H = zg*hs + (1.f - zg)*ht;
        Hls[row*64 + cs*8 + (col & 7)] = f2b(H);
      }
    }
  }
  __syncthreads();

  u16* H2ls = Wst;
  f32x4 acc2[2][4] = {};
  #pragma unroll
  for (int ks = 0; ks < 2; ++ks) {
    short8v av[2], bvv[4];
    #pragma unroll
    for (int fm = 0; fm < 2; ++fm) {
      int r = w*32 + fm*16 + lr;
      int ch = (ks*4 + lk) ^ (r & 7);
      av[fm] = *(const short8v*)&Hls[r*64 + ch*8];
    }
    #pragma unroll
    for (int fn = 0; fn < 4; ++fn) {
      int n = fn*16 + lr;
      int ch = (ks*4 + lk) ^ (n & 7);
      bvv[fn] = *(const short8v*)&W1ls[n*64 + ch*8];
    }
    #pragma unroll
    for (int fm = 0; fm < 2; ++fm)
      #pragma unroll
      for (int fn = 0; fn < 4; ++fn)
        acc2[fm][fn] = __builtin_amdgcn_mfma_f32_16x16x32_bf16(av[fm], bvv[fn], acc2[fm][fn], 0, 0, 0);
  }
  __syncthreads();
  #pragma unroll
  for (int fm = 0; fm < 2; ++fm) {
    #pragma unroll
    for (int fn = 0; fn < 4; ++fn) {
      int col = fn*16 + lr;
      float bias = bh1[col];
      #pragma unroll
      for (int j = 0; j < 4; ++j) {
        int row = w*32 + fm*16 + lk*4 + j;
        float val = acc2[fm][fn][j] + bias;
        int cs = (col >> 3) ^ (row & 7);
        H2ls[row*64 + cs*8 + (col & 7)] = f2b(fmaxf(val, 0.f));
      }
    }
  }
  __syncthreads();

  f32x4 acc3[2][4] = {};
  #pragma unroll
  for (int ks = 0; ks < 2; ++ks) {
    short8v av[2], bvv[4];
    #pragma unroll
    for (int fm = 0; fm < 2; ++fm) {
      int r = w*32 + fm*16 + lr;
      int ch = (ks*4 + lk) ^ (r & 7);
      av[fm] = *(const short8v*)&H2ls[r*64 + ch*8];
    }
    #pragma unroll
    for (int fn = 0; fn < 4; ++fn) {
      int n = fn*16 + lr;
      int ch = (ks*4 + lk) ^ (n & 7);
      bvv[fn] = *(const short8v*)&W2ls[n*64 + ch*8];
    }
    #pragma unroll
    for (int fm = 0; fm < 2; ++fm)
      #pragma unroll
      for (int fn = 0; fn < 4; ++fn)
        acc3[fm][fn] = __builtin_amdgcn_mfma_f32_16x16x32_bf16(av[fm], bvv[fn], acc3[fm][fn], 0, 0, 0);
  }
  #pragma unroll
  for (int fm = 0; fm < 2; ++fm) {
    #pragma unroll
    for (int fn = 0; fn < 4; ++fn) {
      int col = fn*16 + lr;
      float bias = bh2[col];
      #pragma unroll
      for (int j = 0; j < 4; ++j) {
        int row = w*32 + fm*16 + lk*4 + j;
        size_t gi = (size_t)(m0 + row)*64 + col;
        out[gi] = X[gi] + acc3[fm][fn][j] + bias;
      }
    }
  }
}

extern "C" void kernel_launch(void* const* d_in, const int* in_sizes, int n_in,
                              void* d_out, int out_size, void* d_ws, size_t ws_size,
                              hipStream_t stream) {
  const float* X    = (const float*)d_in[0];
  const float* STE  = (const float*)d_in[1];
  const float* adj  = (const float*)d_in[2];
  const float* feat0= (const float*)d_in[3];
  const float* feat1= (const float*)d_in[4];
  const float* Wq0  = (const float*)d_in[5];
  const float* Wk0  = (const float*)d_in[6];
  const float* Wq1  = (const float*)d_in[7];
  const float* Wk1  = (const float*)d_in[8];
  const float* Wgcn = (const float*)d_in[9];
  const float* bgcn = (const float*)d_in[10];
  const float* Wq   = (const float*)d_in[11];
  const float* bq   = (const float*)d_in[12];
  const float* Wk   = (const float*)d_in[13];
  const float* bk   = (const float*)d_in[14];
  const float* Wv   = (const float*)d_in[15];
  const float* bv   = (const float*)d_in[16];
  const float* Wx1  = (const float*)d_in[17];
  const float* bx1  = (const float*)d_in[18];
  const float* Wx2  = (const float*)d_in[19];
  const float* bx2  = (const float*)d_in[20];
  const float* Ws   = (const float*)d_in[21];
  const float* Wt   = (const float*)d_in[22];
  const float* btb  = (const float*)d_in[23];
  const float* Wh1  = (const float*)d_in[24];
  const float* bh1  = (const float*)d_in[25];
  const float* Wh2  = (const float*)d_in[26];
  const float* bh2  = (const float*)d_in[27];
  (void)in_sizes; (void)n_in; (void)out_size;

  const size_t NEEDED = 164626432ull;
  if (ws_size < NEEDED) return;

  char* w = (char*)d_ws;
  float* fe    = (float*)(w);
  u8*    Acat8 = (u8*)(w + 1048576);
  u16*   Wqkvt = (u16*)(w + 7340032);
  u16*   W1t   = (u16*)(w + 7389184);
  u16*   W2t   = (u16*)(w + 7397376);
  u16*   Wstt  = (u16*)(w + 7405568);
  u16*   Wh1t  = (u16*)(w + 7421952);
  u16*   Wh2t  = (u16*)(w + 7430144);
  u16*   Wgcnt = (u16*)(w + 7438336);
  float* feKt  = (float*)(w + 7471104);
  u8*    Yt2   = (u8*)(w + 13631488);
  u8*    Yt3   = (u8*)(w + 63963136);
  u16*   HSb   = (u16*)(w + 114294784);
  u8*    Yt1   = (u8*)d_out;
  u16*   HTb   = (u16*)(w + 13631488);   // reuses Yt2 slot after k_spatial

  k_pre<<<2112, 256, 0, stream>>>(feat0, feat1, Wq0, Wk0, Wq1, Wk1, adj,
                                  Wq, Wk, Wv, Wx1, Wx2, Ws, Wt, Wh1, Wh2, Wgcn,
                                  fe, feKt, Acat8, Wqkvt, W1t, W2t, Wstt, Wh1t, Wh2t, Wgcnt);
  k_graph_softmax<<<dim3(N_, 2), 256, 0, stream>>>(fe, feKt, Acat8);
  k_xw_mfma<<<NROWS_/128, 256, 0, stream>>>(X, Wgcnt, HSb, Yt1, Yt2, Yt3);
  k_spatial_mfma<<<dim3(8, BT_/2), 256, 0, stream>>>(Acat8, Yt1, Yt2, Yt3, bgcn, HSb);
  k_attn_ht<<<(B_*N_)/4, 256, 0, stream>>>(X, STE, Wqkvt, bq, bk, bv,
                                           W1t, W2t, bx1, bx2, HTb);
  k_fusion_mfma<<<NROWS_/128, 256, 0, stream>>>(X, HSb, HTb, Wstt, Wh1t, Wh2t,
                                                btb, bh1, bh2, (float*)d_out);
}

// Round 18
// 464.040 us; speedup vs baseline: 1.2841x; 1.2841x over previous
//
#include <hip/hip_runtime.h>
#include <hip/hip_bf16.h>
#include <hip/hip_fp8.h>
#include <stdint.h>

#define B_ 32
#define T_ 12
#define N_ 1024
#define D_ 64
#define F_ 16
#define KH_ 8
#define BT_ (B_*T_)
#define NROWS_ (BT_*N_)
#define K3_ 3072

typedef unsigned short u16;
typedef unsigned char u8;
struct __align__(8) u16x4 { u16 x, y, z, w; };
struct __align__(16) u16x8 { u16 v[8]; };
typedef __attribute__((ext_vector_type(8))) short short8v;
typedef __attribute__((ext_vector_type(4))) float f32x4;
typedef __attribute__((ext_vector_type(2))) long long2v;

__device__ __forceinline__ float b2f(u16 u) {
  union { float f; unsigned int i; } c; c.i = ((unsigned int)u) << 16; return c.f;
}
__device__ __forceinline__ u16 f2b(float f) {
  union { float f; unsigned int i; } c; c.f = f;
  unsigned int u = c.i;
  unsigned int r = ((u >> 16) & 1u) + 0x7FFFu;
  return (u16)((u + r) >> 16);
}
__device__ __forceinline__ u8 f2e4(float f) {
  __hip_fp8_e4m3 h(f);
  return (u8)h.__x;
}
__device__ __forceinline__ unsigned cvt_pk_bf16(float lo, float hi) {
  unsigned r;
  asm volatile("v_cvt_pk_bf16_f32 %0, %1, %2" : "=v"(r) : "v"(lo), "v"(hi));
  return r;
}
// k-interleave perm: logical k-group g (0..7) within a 64-byte block -> byte (g&3)*16+(g>>2)*8
__device__ __forceinline__ int kperm(int c) {
  int g = (c >> 3) & 7, e = c & 7;
  return (c & ~63) | ((g & 3) << 4) | ((g >> 2) << 3) | e;
}

__device__ __forceinline__ void gload_lds16(const void* g, void* l) {
  __builtin_amdgcn_global_load_lds(
      (const __attribute__((address_space(1))) unsigned int*)g,
      (__attribute__((address_space(3))) unsigned int*)l, 16, 0, 0);
}

// ---- K0 (merged): fe = relu(feat@W) (+ transposed K copies) | adj copy (fp8 x256, k-perm) | weight transposes.
__global__ __launch_bounds__(256) void k_pre(
    const float* __restrict__ feat0, const float* __restrict__ feat1,
    const float* __restrict__ Wq0, const float* __restrict__ Wk0,
    const float* __restrict__ Wq1, const float* __restrict__ Wk1,
    const float* __restrict__ adj,
    const float* __restrict__ Wq, const float* __restrict__ Wk,
    const float* __restrict__ Wv,
    const float* __restrict__ Wx1, const float* __restrict__ Wx2,
    const float* __restrict__ Ws, const float* __restrict__ Wt,
    const float* __restrict__ Wh1, const float* __restrict__ Wh2,
    const float* __restrict__ Wgcn,
    float* __restrict__ fe, float* __restrict__ feKt, u8* __restrict__ Acat8,
    u16* __restrict__ Wqkvt, u16* __restrict__ W1t, u16* __restrict__ W2t,
    u16* __restrict__ Wstt, u16* __restrict__ Wh1t, u16* __restrict__ Wh2t,
    u16* __restrict__ Wgcnt)
{
  int bid = blockIdx.x;
  int t = threadIdx.x;
  if (bid < 1024) {
    int r = bid;
    int m = t >> 6, d = t & 63;
    const float* feat = (m < 2) ? feat0 : feat1;
    const float* W = (m == 0) ? Wq0 : (m == 1) ? Wk0 : (m == 2) ? Wq1 : Wk1;
    float acc = 0.f;
    #pragma unroll
    for (int ff = 0; ff < F_; ++ff) acc += feat[r*F_ + ff] * W[ff*D_ + d];
    float val = fmaxf(acc, 0.f);
    fe[((size_t)m*N_ + r)*D_ + d] = val;
    if (m & 1) {
      int g = m >> 1;
      feKt[((size_t)g*D_ + d)*N_ + r] = val;
    }
  } else if (bid < 2048) {
    int r = bid - 1024;
    for (int c = t; c < N_; c += 256)
      Acat8[(size_t)r*K3_ + kperm(c)] = f2e4(adj[(size_t)r*N_ + c] * 256.0f);
  } else {
    int g0 = (bid - 2048)*256 + t;
    const int stride = 64*256;
    for (int i = g0; i < 192*128; i += stride) {
      int nn = i >> 7, kk = i & 127;
      const float* W = (nn < 64) ? Wq : (nn < 128) ? Wk : Wv;
      Wqkvt[i] = f2b(W[kk*64 + (nn & 63)]);
    }
    for (int i = g0; i < 64*64; i += stride) {
      int nn = i >> 6, kk = i & 63;
      W1t[i] = f2b(Wx1[kk*64 + nn]);
      W2t[i] = f2b(Wx2[kk*64 + nn]);
      Wh1t[i] = f2b(Wh1[kk*64 + nn]);
      Wh2t[i] = f2b(Wh2[kk*64 + nn]);
    }
    for (int i = g0; i < 64*128; i += stride) {
      int nn = i >> 7, kk = i & 127;
      Wstt[i] = f2b((kk < 64) ? Ws[kk*64 + nn] : Wt[(kk-64)*64 + nn]);
    }
    for (int i = g0; i < 256*64; i += stride) {
      int cc = i >> 6, kk = i & 63;
      Wgcnt[i] = f2b(Wgcn[(size_t)((cc >> 6)*64 + kk)*64 + (cc & 63)]);
    }
  }
}

// ---- K1: S_g = softmax(FEQ @ FEK^T / 8) rows -> Acat8 (fp8, x256, k-perm), coalesced via feKt
__global__ __launch_bounds__(256) void k_graph_softmax(const float* __restrict__ fe,
                                                       const float* __restrict__ feKt,
                                                       u8* __restrict__ Acat8) {
  int r = blockIdx.x, g = blockIdx.y;
  const float* FEQ = fe + (size_t)(g*2 + 0)*N_*D_;
  const float* Kt  = feKt + (size_t)g*D_*N_;
  __shared__ float q[D_];
  __shared__ float red[256];
  int tid = threadIdx.x;
  if (tid < D_) q[tid] = FEQ[(size_t)r*D_ + tid];
  __syncthreads();
  float lg[4] = {0.f, 0.f, 0.f, 0.f};
  for (int f = 0; f < D_; ++f) {
    float qf = q[f];
    const float* kt = Kt + (size_t)f*N_;
    #pragma unroll
    for (int j = 0; j < 4; ++j) lg[j] += qf * kt[tid + j*256];
  }
  float mx = -1e30f;
  #pragma unroll
  for (int j = 0; j < 4; ++j) { lg[j] *= 0.125f; mx = fmaxf(mx, lg[j]); }
  red[tid] = mx; __syncthreads();
  for (int s = 128; s > 0; s >>= 1) { if (tid < s) red[tid] = fmaxf(red[tid], red[tid+s]); __syncthreads(); }
  mx = red[0]; __syncthreads();
  float sum = 0.f;
  #pragma unroll
  for (int j = 0; j < 4; ++j) { lg[j] = __expf(lg[j]-mx); sum += lg[j]; }
  red[tid] = sum; __syncthreads();
  for (int s = 128; s > 0; s >>= 1) { if (tid < s) red[tid] += red[tid+s]; __syncthreads(); }
  float inv = 256.0f / red[0];
  #pragma unroll
  for (int j = 0; j < 4; ++j) {
    int c = tid + j*256;
    Acat8[(size_t)r*K3_ + (1+g)*N_ + kperm(c)] = f2e4(lg[j]*inv);
  }
}

// ---- K2 (MFMA): [BTN,64] @ Wgcnt^T[64,256] -> G0 bf16 row-major + Yt1..3 fp8 transposed (k-perm node axis)
__global__ __launch_bounds__(256) void k_xw_mfma(
    const float* __restrict__ X, const u16* __restrict__ Wgcnt,
    u16* __restrict__ G0, u8* __restrict__ Yt1, u8* __restrict__ Yt2, u8* __restrict__ Yt3)
{
  __shared__ __align__(16) u16 SM[24576];
  u16* Als = SM;
  u16* Bls = SM + 8192;
  u8*  T8  = (u8*)SM;
  u16* Gls = SM;
  int m0 = blockIdx.x * 128;
  int t = threadIdx.x;
  int w = t >> 6, l = t & 63;

  {
    int rsub = l >> 3, pch = l & 7;
    #pragma unroll
    for (int i = 0; i < 8; ++i) {
      int R0 = w*64 + i*8;
      int n = R0 + rsub;
      int q = pch ^ (n & 7);
      gload_lds16(Wgcnt + (size_t)n*64 + q*8, &Bls[R0*64]);
    }
  }
  #pragma unroll
  for (int i = 0; i < 4; ++i) {
    int flat = t + 256*i;
    int row = flat >> 3, c = flat & 7;
    const float* src = X + (size_t)(m0+row)*64 + c*8;
    float4 f0 = *(const float4*)src;
    float4 f1 = *(const float4*)(src + 4);
    u16x8 pk;
    pk.v[0]=f2b(f0.x); pk.v[1]=f2b(f0.y); pk.v[2]=f2b(f0.z); pk.v[3]=f2b(f0.w);
    pk.v[4]=f2b(f1.x); pk.v[5]=f2b(f1.y); pk.v[6]=f2b(f1.z); pk.v[7]=f2b(f1.w);
    int cs = c ^ (row & 7);
    *(u16x8*)&Als[row*64 + cs*8] = pk;
  }
  __syncthreads();

  int wm = w & 1, wn = w >> 1;
  int lr = l & 15, lk = l >> 4;
  f32x4 acc[4][8] = {};
  #pragma unroll
  for (int ks = 0; ks < 2; ++ks) {
    short8v av[4], bv[8];
    #pragma unroll
    for (int fm = 0; fm < 4; ++fm) {
      int r = wm*64 + fm*16 + lr;
      int ch = (ks*4 + lk) ^ (r & 7);
      av[fm] = *(const short8v*)&Als[r*64 + ch*8];
    }
    #pragma unroll
    for (int fn = 0; fn < 8; ++fn) {
      int n = wn*128 + fn*16 + lr;
      int ch = (ks*4 + lk) ^ (n & 7);
      bv[fn] = *(const short8v*)&Bls[n*64 + ch*8];
    }
    #pragma unroll
    for (int fm = 0; fm < 4; ++fm)
      #pragma unroll
      for (int fn = 0; fn < 8; ++fn)
        acc[fm][fn] = __builtin_amdgcn_mfma_f32_16x16x32_bf16(av[fm], bv[fn], acc[fm][fn], 0, 0, 0);
  }
  __syncthreads();

  #pragma unroll
  for (int fm = 0; fm < 4; ++fm) {
    int row0 = wm*64 + fm*16 + lk*4;
    #pragma unroll
    for (int fn = 0; fn < 8; ++fn) {
      int c = wn*128 + fn*16 + lr;
      if (c >= 64) {
        int dp = c - 64;
        unsigned pk = (unsigned)f2e4(acc[fm][fn][0])
                    | ((unsigned)f2e4(acc[fm][fn][1]) << 8)
                    | ((unsigned)f2e4(acc[fm][fn][2]) << 16)
                    | ((unsigned)f2e4(acc[fm][fn][3]) << 24);
        *(unsigned*)&T8[dp*128 + (row0 ^ ((dp & 7) << 3))] = pk;
      }
    }
  }
  __syncthreads();
  {
    int bt = m0 >> 10, nb = m0 & 1023;
    #pragma unroll
    for (int i = 0; i < 12; ++i) {
      int cc = t + 256*i;
      int dp = cc >> 4, nc = cc & 15;
      int n0 = nc*8;
      unsigned long long v8 = *(const unsigned long long*)&T8[dp*128 + (n0 ^ ((dp & 7) << 3))];
      int p = dp >> 6, d = dp & 63;
      u8* Yt = (p == 0) ? Yt1 : (p == 1) ? Yt2 : Yt3;
      int gq = (n0 >> 3) & 7;
      int n0p = (n0 & ~63) | ((gq & 3) << 4) | ((gq >> 2) << 3);
      *(unsigned long long*)&Yt[((size_t)bt*64 + d)*1024 + nb + n0p] = v8;
    }
  }
  __syncthreads();

  if (wn == 0) {
    #pragma unroll
    for (int fm = 0; fm < 4; ++fm) {
      int row0 = wm*64 + fm*16 + lk*4;
      #pragma unroll
      for (int fn = 0; fn < 4; ++fn) {
        int c = fn*16 + lr;
        #pragma unroll
        for (int j = 0; j < 4; ++j) {
          int row = row0 + j;
          Gls[row*64 + (c ^ ((row & 7) << 3))] = f2b(acc[fm][fn][j]);
        }
      }
    }
  }
  __syncthreads();
  #pragma unroll
  for (int i = 0; i < 4; ++i) {
    int cc = t + 256*i;
    int row = cc >> 3, ch = cc & 7;
    u16x8 vv = *(const u16x8*)&Gls[row*64 + ((ch*8) ^ ((row & 7) << 3))];
    *(u16x8*)&G0[(size_t)(m0 + row)*64 + ch*8] = vv;
  }
}

// ---- K3 (MFMA fp8): per bt-pair, C[128,128] = (256*Acat)[128,3072] @ Ystack; HS = relu(C/256 + G0 + b)
// k-interleaved memory: one ds_read_b128 per fragment yields both ks operands (conflict-free).
#define BM 128
#define BK3 64
#define NKT3 (K3_/BK3)   // 48
__global__ __launch_bounds__(256) void k_spatial_mfma(
    const u8* __restrict__ Acat8,
    const u8* __restrict__ Yt1, const u8* __restrict__ Yt2, const u8* __restrict__ Yt3,
    const float* __restrict__ bgcn,
    u16* __restrict__ HS)
{
  __shared__ __align__(16) u8 SM8[32768];
  int f = blockIdx.x + 8*blockIdx.y;
  int u = f & 7, v = f >> 3;
  int btp = u*24 + (v >> 3);
  int m0  = (v & 7) * BM;
  int bt0 = btp * 2;

  int t = threadIdx.x;
  int w = t >> 6, l = t & 63;
  int rsub = l >> 2, pch = l & 3;

  f32x4 acc[4][4] = {};
  int wm = w >> 1, wn = w & 1;
  int lr = l & 15, lk = l >> 4;

  const u8* aSrc[2];
  size_t bOff[2];
  int R0s[2];
  #pragma unroll
  for (int i = 0; i < 2; ++i) {
    int row = w*32 + i*16 + rsub;
    int q = pch ^ ((row >> 1) & 3);
    aSrc[i] = Acat8 + (size_t)(m0 + row)*K3_ + q*16;
    int bt = bt0 + (row >> 6), d = row & 63;
    bOff[i] = ((size_t)bt*64 + d)*1024 + q*16;
    R0s[i] = w*32 + i*16;
  }

  #pragma unroll
  for (int i = 0; i < 2; ++i) {
    gload_lds16(aSrc[i], &SM8[R0s[i]*64]);
    gload_lds16(Yt1 + bOff[i], &SM8[16384 + R0s[i]*64]);
  }
  __syncthreads();

  int buf = 0;
  for (int kt = 0; kt < NKT3; ++kt) {
    if (kt + 1 < NKT3) {
      int k0 = (kt + 1) * BK3;
      int pl = k0 >> 10, kk = k0 & 1023;
      const u8* Yt = (pl == 0) ? Yt1 : (pl == 1) ? Yt2 : Yt3;
      int bo = (buf ^ 1) * 8192;
      #pragma unroll
      for (int i = 0; i < 2; ++i) {
        gload_lds16(aSrc[i] + k0, &SM8[bo + R0s[i]*64]);
        gload_lds16(Yt + bOff[i] + kk, &SM8[16384 + bo + R0s[i]*64]);
      }
    }
    const u8* A8 = SM8 + buf*8192;
    const u8* B8 = SM8 + 16384 + buf*8192;
    long2v av[4], bv[4];
    #pragma unroll
    for (int fm = 0; fm < 4; ++fm) {
      int r = wm*64 + fm*16 + lr;
      int sl = lk ^ ((r >> 1) & 3);
      av[fm] = *(const long2v*)(A8 + r*64 + sl*16);
    }
    #pragma unroll
    for (int fn = 0; fn < 4; ++fn) {
      int n = wn*64 + fn*16 + lr;
      int sl = lk ^ ((n >> 1) & 3);
      bv[fn] = *(const long2v*)(B8 + n*64 + sl*16);
    }
    #pragma unroll
    for (int ks = 0; ks < 2; ++ks)
      #pragma unroll
      for (int fm = 0; fm < 4; ++fm)
        #pragma unroll
        for (int fn = 0; fn < 4; ++fn)
          acc[fm][fn] = __builtin_amdgcn_mfma_f32_16x16x32_fp8_fp8(av[fm][ks], bv[fn][ks], acc[fm][fn], 0, 0, 0);
    __syncthreads();
    buf ^= 1;
  }

  u16* Tls = (u16*)SM8;
  #pragma unroll
  for (int fm = 0; fm < 4; ++fm) {
    #pragma unroll
    for (int fn = 0; fn < 4; ++fn) {
      int col = wn*64 + fn*16 + lr;
      int cc = col >> 3, cw = col & 7;
      #pragma unroll
      for (int j = 0; j < 4; ++j) {
        int node = wm*64 + fm*16 + lk*4 + j;
        int sc = cc ^ (node & 7);
        Tls[node*128 + sc*8 + cw] = f2b(acc[fm][fn][j] * 0.00390625f);
      }
    }
  }
  __syncthreads();
  #pragma unroll
  for (int i = 0; i < 8; ++i) {
    int flat = t + 256*i;
    int node = flat >> 4, cc = flat & 15;
    int sc = cc ^ (node & 7);
    u16x8 zv = *(const u16x8*)&Tls[node*128 + sc*8];
    int bt = bt0 + (cc >> 3), d0 = (cc & 7)*8;
    size_t idx = ((size_t)bt*N_ + (m0 + node))*64 + d0;
    u16x8 gv = *(const u16x8*)&HS[idx];
    float4 b0 = *(const float4*)&bgcn[d0];
    float4 b1 = *(const float4*)&bgcn[d0 + 4];
    float bb[8] = { b0.x, b0.y, b0.z, b0.w, b1.x, b1.y, b1.z, b1.w };
    u16x8 ov;
    #pragma unroll
    for (int e = 0; e < 8; ++e) {
      float vv2 = b2f(zv.v[e]) + b2f(gv.v[e]) + bb[e];
      ov.v[e] = f2b(fmaxf(vv2, 0.f));
    }
    *(u16x8*)&HS[idx] = ov;
  }
}

// ---- K4a (MFMA): qkv = relu([X|STE] @ Wqkv^T + b) -> q,k,v bf16 [BTN][64]
__global__ __launch_bounds__(256) void k_qkv(
    const float* __restrict__ X, const float* __restrict__ STE,
    const u16* __restrict__ Wqkvt,
    const float* __restrict__ bq, const float* __restrict__ bk, const float* __restrict__ bv,
    u16* __restrict__ qb, u16* __restrict__ kb, u16* __restrict__ vb)
{
  __shared__ __align__(16) u16 Als[128*128];
  __shared__ __align__(16) u16 Bls[192*128];
  int m0 = blockIdx.x * 128;
  int t = threadIdx.x;
  int w = t >> 6, l = t & 63;

  {
    int rsub = l >> 4, pch = l & 15;
    #pragma unroll
    for (int i = 0; i < 12; ++i) {
      int R0 = w*48 + i*4;
      int n = R0 + rsub;
      int sq = pch ^ (n & 7);
      gload_lds16(Wqkvt + (size_t)n*128 + sq*8, &Bls[R0*128]);
    }
  }
  #pragma unroll
  for (int i = 0; i < 8; ++i) {
    int flat = t + 256*i;
    int row = flat >> 4, c = flat & 15;
    const float* src = ((c < 8) ? X : STE) + (size_t)(m0+row)*64 + (c & 7)*8;
    float4 f0 = *(const float4*)src;
    float4 f1 = *(const float4*)(src + 4);
    u16x8 pk;
    pk.v[0]=f2b(f0.x); pk.v[1]=f2b(f0.y); pk.v[2]=f2b(f0.z); pk.v[3]=f2b(f0.w);
    pk.v[4]=f2b(f1.x); pk.v[5]=f2b(f1.y); pk.v[6]=f2b(f1.z); pk.v[7]=f2b(f1.w);
    int cs = c ^ (row & 7);
    *(u16x8*)&Als[row*128 + cs*8] = pk;
  }
  __syncthreads();

  int wm = w >> 1, wn = w & 1;
  int lr = l & 15, lk = l >> 4;
  f32x4 acc[4][6] = {};
  #pragma unroll
  for (int ks = 0; ks < 4; ++ks) {
    short8v av[4], bvv[6];
    #pragma unroll
    for (int fm = 0; fm < 4; ++fm) {
      int r = wm*64 + fm*16 + lr;
      int ch = (ks*4 + lk) ^ (r & 7);
      av[fm] = *(const short8v*)&Als[r*128 + ch*8];
    }
    #pragma unroll
    for (int fn = 0; fn < 6; ++fn) {
      int n = wn*96 + fn*16 + lr;
      int ch = (ks*4 + lk) ^ (n & 7);
      bvv[fn] = *(const short8v*)&Bls[n*128 + ch*8];
    }
    #pragma unroll
    for (int fm = 0; fm < 4; ++fm)
      #pragma unroll
      for (int fn = 0; fn < 6; ++fn)
        acc[fm][fn] = __builtin_amdgcn_mfma_f32_16x16x32_bf16(av[fm], bvv[fn], acc[fm][fn], 0, 0, 0);
  }

  #pragma unroll
  for (int fm = 0; fm < 4; ++fm) {
    int rowb = m0 + wm*64 + fm*16 + lk*4;
    #pragma unroll
    for (int fn = 0; fn < 6; ++fn) {
      int col = wn*96 + fn*16 + lr;
      int sel = col >> 6, d = col & 63;
      u16* dst = (sel == 0) ? qb : (sel == 1) ? kb : vb;
      float bias = ((sel == 0) ? bq : (sel == 1) ? bk : bv)[d];
      #pragma unroll
      for (int j = 0; j < 4; ++j) {
        float val = acc[fm][fn][j] + bias;
        dst[(size_t)(rowb + j)*64 + d] = f2b(fmaxf(val, 0.f));
      }
    }
  }
}

// ---- K4b (fused): MFMA attention (per head 16x16x32, zero-padded) + HT GEMMs.
__global__ __launch_bounds__(256) void k_attn_ht(
    const u16* __restrict__ qb, const u16* __restrict__ kb, const u16* __restrict__ vb,
    const u16* __restrict__ W1t, const u16* __restrict__ W2t,
    const float* __restrict__ bx1, const float* __restrict__ bx2,
    u16* __restrict__ HT)
{
  __shared__ __align__(16) u16 QS[4][12*64];
  __shared__ __align__(16) u16 KS[4][12*64];
  __shared__ __align__(16) u16 VT[4][64*24];
  __shared__ __align__(16) u16 Ols[48*64];
  __shared__ __align__(16) u16 H1ls[48*64];
  __shared__ __align__(16) u16 W1ls[64*64];
  __shared__ __align__(16) u16 W2ls[64*64];
  int t = threadIdx.x;
  int w = t >> 6, l = t & 63;

  {
    int rsub = l >> 3, pch = l & 7;
    #pragma unroll
    for (int i = 0; i < 2; ++i) {
      int R0 = w*16 + i*8;
      int row = R0 + rsub;
      int sq = pch ^ (row & 7);
      gload_lds16(W1t + (size_t)row*64 + sq*8, &W1ls[R0*64]);
      gload_lds16(W2t + (size_t)row*64 + sq*8, &W2ls[R0*64]);
    }
  }

  int flat = blockIdx.x*4 + w;
  int b = flat >> 10, n = flat & 1023;
  {
    int ch = l >> 3, e = l & 7;
    #pragma unroll
    for (int tt = 0; tt < T_; ++tt) {
      size_t idx = ((size_t)(b*T_ + tt)*N_ + n)*64 + l;
      u16 qv = qb[idx], kv = kb[idx], vv = vb[idx];
      int sl = (ch ^ (tt & 7))*8 + e;
      QS[w][tt*64 + sl] = qv;
      KS[w][tt*64 + sl] = kv;
      VT[w][l*24 + tt] = vv;
    }
    #pragma unroll
    for (int tt = T_; tt < 16; ++tt) VT[w][l*24 + tt] = 0;
  }
  __syncthreads();

  int g = l >> 4;
  int sr = l & 15;
  short8v z8 = {0,0,0,0,0,0,0,0};
  float scale = 0.3535533906f;

  for (int h = 0; h < KH_; ++h) {
    short8v kf = *(const short8v*)&KS[w][sr*64 + ((h ^ (sr & 7)) << 3)];
    short8v qf = *(const short8v*)&QS[w][sr*64 + ((h ^ (sr & 7)) << 3)];
    short8v avk = (l < 16) ? kf : z8;
    short8v bvq = (l < 16) ? qf : z8;
    f32x4 zc = {0.f, 0.f, 0.f, 0.f};
    f32x4 S = __builtin_amdgcn_mfma_f32_16x16x32_bf16(avk, bvq, zc, 0, 0, 0);
    float sc0 = S[0]*scale, sc1 = S[1]*scale, sc2 = S[2]*scale, sc3 = S[3]*scale;
    bool gv = (g < 3);
    float mown = gv ? fmaxf(fmaxf(sc0, sc1), fmaxf(sc2, sc3)) : -1e30f;
    float m1 = fmaxf(mown, __shfl_xor(mown, 16));
    float m2 = fmaxf(m1, __shfl_xor(m1, 48));
    float e0 = gv ? __expf(sc0 - m2) : 0.f;
    float e1 = gv ? __expf(sc1 - m2) : 0.f;
    float e2 = gv ? __expf(sc2 - m2) : 0.f;
    float e3 = gv ? __expf(sc3 - m2) : 0.f;
    float ss = e0 + e1 + e2 + e3;
    float s1 = ss + __shfl_xor(ss, 16);
    float s2 = s1 + __shfl_xor(s1, 48);
    float rn = 1.0f / s2;
    float p0 = e0*rn, p1 = e1*rn, p2 = e2*rn, p3 = e3*rn;
    float pa0 = __shfl_xor(p0, 16), pa1 = __shfl_xor(p1, 16),
          pa2 = __shfl_xor(p2, 16), pa3 = __shfl_xor(p3, 16);
    float pb0 = __shfl_xor(p0, 48), pb1 = __shfl_xor(p1, 48),
          pb2 = __shfl_xor(p2, 48), pb3 = __shfl_xor(p3, 48);
    float v0, v1, v2, v3, v4, v5, v6, v7;
    if (g == 0)      { v0=p0;  v1=p1;  v2=p2;  v3=p3;  v4=pa0; v5=pa1; v6=pa2; v7=pa3; }
    else if (g == 1) { v0=pb0; v1=pb1; v2=pb2; v3=pb3; v4=0;   v5=0;   v6=0;   v7=0;   }
    else             { v0=0; v1=0; v2=0; v3=0; v4=0; v5=0; v6=0; v7=0; }
    union { unsigned u[4]; short8v s; } pk;
    pk.u[0] = cvt_pk_bf16(v0, v1);
    pk.u[1] = cvt_pk_bf16(v2, v3);
    pk.u[2] = cvt_pk_bf16(v4, v5);
    pk.u[3] = cvt_pk_bf16(v6, v7);
    int vrow = h*8 + (l & 7);
    short8v vf = *(const short8v*)&VT[w][vrow*24 + ((l >> 4) & 1)*8];
    short8v av2 = (g < 2) ? vf : z8;
    f32x4 O = __builtin_amdgcn_mfma_f32_16x16x32_bf16(av2, pk.s, zc, 0, 0, 0);
    if (g < 2 && sr < T_) {
      int r = w*T_ + sr;
      unsigned lo = cvt_pk_bf16(O[0], O[1]);
      unsigned hi = cvt_pk_bf16(O[2], O[3]);
      unsigned off = (unsigned)(r*64 + ((h ^ (r & 7)) << 3) + g*4);
      uint2 pr; pr.x = lo; pr.y = hi;
      *(uint2*)&Ols[off] = pr;
    }
  }
  __syncthreads();

  int lr = l & 15, lk = l >> 4;
  int col = w*16 + lr;
  f32x4 acc1[3] = {};
  #pragma unroll
  for (int ks = 0; ks < 2; ++ks) {
    short8v av[3], bvv;
    #pragma unroll
    for (int fm = 0; fm < 3; ++fm) {
      int r = fm*16 + lr;
      int ch = (ks*4 + lk) ^ (r & 7);
      av[fm] = *(const short8v*)&Ols[r*64 + ch*8];
    }
    {
      int nn = w*16 + lr;
      int ch = (ks*4 + lk) ^ (nn & 7);
      bvv = *(const short8v*)&W1ls[nn*64 + ch*8];
    }
    #pragma unroll
    for (int fm = 0; fm < 3; ++fm)
      acc1[fm] = __builtin_amdgcn_mfma_f32_16x16x32_bf16(av[fm], bvv, acc1[fm], 0, 0, 0);
  }
  {
    float bias1 = bx1[col];
    #pragma unroll
    for (int fm = 0; fm < 3; ++fm)
      #pragma unroll
      for (int j = 0; j < 4; ++j) {
        int r = fm*16 + lk*4 + j;
        H1ls[r*64 + ((col >> 3) ^ (r & 7))*8 + (col & 7)] = f2b(fmaxf(acc1[fm][j] + bias1, 0.f));
      }
  }
  __syncthreads();

  f32x4 acc2[3] = {};
  #pragma unroll
  for (int ks = 0; ks < 2; ++ks) {
    short8v av[3], bvv;
    #pragma unroll
    for (int fm = 0; fm < 3; ++fm) {
      int r = fm*16 + lr;
      int ch = (ks*4 + lk) ^ (r & 7);
      av[fm] = *(const short8v*)&H1ls[r*64 + ch*8];
    }
    {
      int nn = w*16 + lr;
      int ch = (ks*4 + lk) ^ (nn & 7);
      bvv = *(const short8v*)&W2ls[nn*64 + ch*8];
    }
    #pragma unroll
    for (int fm = 0; fm < 3; ++fm)
      acc2[fm] = __builtin_amdgcn_mfma_f32_16x16x32_bf16(av[fm], bvv, acc2[fm], 0, 0, 0);
  }
  {
    float bias2 = bx2[col];
    #pragma unroll
    for (int fm = 0; fm < 3; ++fm)
      #pragma unroll
      for (int j = 0; j < 4; ++j) {
        int r = fm*16 + lk*4 + j;
        int fp = blockIdx.x*4 + (r / T_);
        int tt = r % T_;
        int b2 = fp >> 10, n2 = fp & 1023;
        HT[((size_t)(b2*T_ + tt)*N_ + n2)*64 + col] = f2b(acc2[fm][j] + bias2);
      }
  }
}

// ---- K5 (MFMA): gated fusion + output head, 128 rows/block, all-LDS chain
__global__ __launch_bounds__(256) void k_fusion_mfma(
    const float* __restrict__ X,
    const u16* __restrict__ HS, const u16* __restrict__ HT,
    const u16* __restrict__ Wstt, const u16* __restrict__ Wh1t, const u16* __restrict__ Wh2t,
    const float* __restrict__ btb, const float* __restrict__ bh1, const float* __restrict__ bh2,
    float* __restrict__ out)
{
  __shared__ __align__(16) u16 Als[128*128];
  __shared__ __align__(16) u16 Wst[64*128];
  __shared__ __align__(16) u16 W1ls[64*64];
  __shared__ __align__(16) u16 W2ls[64*64];
  __shared__ __align__(16) u16 Hls[128*64];
  int m0 = blockIdx.x * 128;
  int t = threadIdx.x;
  int w = t >> 6, l = t & 63;

  {
    int rsub = l >> 4, pch = l & 15;
    #pragma unroll
    for (int i = 0; i < 8; ++i) {
      int R0 = w*32 + i*4;
      int row = R0 + rsub;
      int q = pch ^ (row & 7);
      const u16* src = (q < 8) ? (HS + (size_t)(m0 + row)*64 + q*8)
                               : (HT + (size_t)(m0 + row)*64 + (q - 8)*8);
      gload_lds16(src, &Als[R0*128]);
    }
    #pragma unroll
    for (int i = 0; i < 4; ++i) {
      int R0 = w*16 + i*4;
      int n = R0 + rsub;
      int q = pch ^ (n & 7);
      gload_lds16(Wstt + (size_t)n*128 + q*8, &Wst[R0*128]);
    }
  }
  {
    int rsub = l >> 3, pch = l & 7;
    #pragma unroll
    for (int i = 0; i < 2; ++i) {
      int R0 = w*16 + i*8;
      int row = R0 + rsub;
      int q = pch ^ (row & 7);
      gload_lds16(Wh1t + (size_t)row*64 + q*8, &W1ls[R0*64]);
      gload_lds16(Wh2t + (size_t)row*64 + q*8, &W2ls[R0*64]);
    }
  }
  __syncthreads();

  int lr = l & 15, lk = l >> 4;
  f32x4 acc1[2][4] = {};
  #pragma unroll
  for (int ks = 0; ks < 4; ++ks) {
    short8v av[2], bvv[4];
    #pragma unroll
    for (int fm = 0; fm < 2; ++fm) {
      int r = w*32 + fm*16 + lr;
      int ch = (ks*4 + lk) ^ (r & 7);
      av[fm] = *(const short8v*)&Als[r*128 + ch*8];
    }
    #pragma unroll
    for (int fn = 0; fn < 4; ++fn) {
      int n = fn*16 + lr;
      int ch = (ks*4 + lk) ^ (n & 7);
      bvv[fn] = *(const short8v*)&Wst[n*128 + ch*8];
    }
    #pragma unroll
    for (int fm = 0; fm < 2; ++fm)
      #pragma unroll
      for (int fn = 0; fn < 4; ++fn)
        acc1[fm][fn] = __builtin_amdgcn_mfma_f32_16x16x32_bf16(av[fm], bvv[fn], acc1[fm][fn], 0, 0, 0);
  }
  #pragma unroll
  for (int fm = 0; fm < 2; ++fm) {
    #pragma unroll
    for (int fn = 0; fn < 4; ++fn) {
      int col = fn*16 + lr;
      float bb = btb[col];
      #pragma unroll
      for (int j = 0; j < 4; ++j) {
        int row = w*32 + fm*16 + lk*4 + j;
        float a_s = acc1[fm][fn][j] + bb;
        float zg = 1.f/(1.f + __expf(-a_s));
        int cs = (col >> 3) ^ (row & 7);
        float hs = b2f(Als[row*128 + cs*8 + (col & 7)]);
        float ht = b2f(Als[row*128 + (cs + 8)*8 + (col & 7)]);
        float H = zg*hs + (1.f - zg)*ht;
        Hls[row*64 + cs*8 + (col & 7)] = f2b(H);
      }
    }
  }
  __syncthreads();

  u16* H2ls = Wst;
  f32x4 acc2[2][4] = {};
  #pragma unroll
  for (int ks = 0; ks < 2; ++ks) {
    short8v av[2], bvv[4];
    #pragma unroll
    for (int fm = 0; fm < 2; ++fm) {
      int r = w*32 + fm*16 + lr;
      int ch = (ks*4 + lk) ^ (r & 7);
      av[fm] = *(const short8v*)&Hls[r*64 + ch*8];
    }
    #pragma unroll
    for (int fn = 0; fn < 4; ++fn) {
      int n = fn*16 + lr;
      int ch = (ks*4 + lk) ^ (n & 7);
      bvv[fn] = *(const short8v*)&W1ls[n*64 + ch*8];
    }
    #pragma unroll
    for (int fm = 0; fm < 2; ++fm)
      #pragma unroll
      for (int fn = 0; fn < 4; ++fn)
        acc2[fm][fn] = __builtin_amdgcn_mfma_f32_16x16x32_bf16(av[fm], bvv[fn], acc2[fm][fn], 0, 0, 0);
  }
  __syncthreads();
  #pragma unroll
  for (int fm = 0; fm < 2; ++fm) {
    #pragma unroll
    for (int fn = 0; fn < 4; ++fn) {
      int col = fn*16 + lr;
      float bias = bh1[col];
      #pragma unroll
      for (int j = 0; j < 4; ++j) {
        int row = w*32 + fm*16 + lk*4 + j;
        float val = acc2[fm][fn][j] + bias;
        int cs = (col >> 3) ^ (row & 7);
        H2ls[row*64 + cs*8 + (col & 7)] = f2b(fmaxf(val, 0.f));
      }
    }
  }
  __syncthreads();

  f32x4 acc3[2][4] = {};
  #pragma unroll
  for (int ks = 0; ks < 2; ++ks) {
    short8v av[2], bvv[4];
    #pragma unroll
    for (int fm = 0; fm < 2; ++fm) {
      int r = w*32 + fm*16 + lr;
      int ch = (ks*4 + lk) ^ (r & 7);
      av[fm] = *(const short8v*)&H2ls[r*64 + ch*8];
    }
    #pragma unroll
    for (int fn = 0; fn < 4; ++fn) {
      int n = fn*16 + lr;
      int ch = (ks*4 + lk) ^ (n & 7);
      bvv[fn] = *(const short8v*)&W2ls[n*64 + ch*8];
    }
    #pragma unroll
    for (int fm = 0; fm < 2; ++fm)
      #pragma unroll
      for (int fn = 0; fn < 4; ++fn)
        acc3[fm][fn] = __builtin_amdgcn_mfma_f32_16x16x32_bf16(av[fm], bvv[fn], acc3[fm][fn], 0, 0, 0);
  }
  #pragma unroll
  for (int fm = 0; fm < 2; ++fm) {
    #pragma unroll
    for (int fn = 0; fn < 4; ++fn) {
      int col = fn*16 + lr;
      float bias = bh2[col];
      #pragma unroll
      for (int j = 0; j < 4; ++j) {
        int row = w*32 + fm*16 + lk*4 + j;
        size_t gi = (size_t)(m0 + row)*64 + col;
        out[gi] = X[gi] + acc3[fm][fn][j] + bias;
      }
    }
  }
}

extern "C" void kernel_launch(void* const* d_in, const int* in_sizes, int n_in,
                              void* d_out, int out_size, void* d_ws, size_t ws_size,
                              hipStream_t stream) {
  const float* X    = (const float*)d_in[0];
  const float* STE  = (const float*)d_in[1];
  const float* adj  = (const float*)d_in[2];
  const float* feat0= (const float*)d_in[3];
  const float* feat1= (const float*)d_in[4];
  const float* Wq0  = (const float*)d_in[5];
  const float* Wk0  = (const float*)d_in[6];
  const float* Wq1  = (const float*)d_in[7];
  const float* Wk1  = (const float*)d_in[8];
  const float* Wgcn = (const float*)d_in[9];
  const float* bgcn = (const float*)d_in[10];
  const float* Wq   = (const float*)d_in[11];
  const float* bq   = (const float*)d_in[12];
  const float* Wk   = (const float*)d_in[13];
  const float* bk   = (const float*)d_in[14];
  const float* Wv   = (const float*)d_in[15];
  const float* bv   = (const float*)d_in[16];
  const float* Wx1  = (const float*)d_in[17];
  const float* bx1  = (const float*)d_in[18];
  const float* Wx2  = (const float*)d_in[19];
  const float* bx2  = (const float*)d_in[20];
  const float* Ws   = (const float*)d_in[21];
  const float* Wt   = (const float*)d_in[22];
  const float* btb  = (const float*)d_in[23];
  const float* Wh1  = (const float*)d_in[24];
  const float* bh1  = (const float*)d_in[25];
  const float* Wh2  = (const float*)d_in[26];
  const float* bh2  = (const float*)d_in[27];
  (void)in_sizes; (void)n_in; (void)out_size;

  const size_t NEEDED = 164626432ull;
  if (ws_size < NEEDED) return;

  char* w = (char*)d_ws;
  float* fe    = (float*)(w);
  u8*    Acat8 = (u8*)(w + 1048576);
  u16*   Wqkvt = (u16*)(w + 7340032);
  u16*   W1t   = (u16*)(w + 7389184);
  u16*   W2t   = (u16*)(w + 7397376);
  u16*   Wstt  = (u16*)(w + 7405568);
  u16*   Wh1t  = (u16*)(w + 7421952);
  u16*   Wh2t  = (u16*)(w + 7430144);
  u16*   Wgcnt = (u16*)(w + 7438336);
  float* feKt  = (float*)(w + 7471104);
  u8*    Yt2   = (u8*)(w + 13631488);
  u8*    Yt3   = (u8*)(w + 63963136);
  u16*   HSb   = (u16*)(w + 114294784);
  u8*    Yt1   = (u8*)d_out;
  u16*   qb    = (u16*)(w + 13631488);
  u16*   kbuf  = (u16*)(w + 63963136);
  u16*   vbuf  = (u16*)d_out;
  u16*   HTb   = qb;

  k_pre<<<2112, 256, 0, stream>>>(feat0, feat1, Wq0, Wk0, Wq1, Wk1, adj,
                                  Wq, Wk, Wv, Wx1, Wx2, Ws, Wt, Wh1, Wh2, Wgcn,
                                  fe, feKt, Acat8, Wqkvt, W1t, W2t, Wstt, Wh1t, Wh2t, Wgcnt);
  k_graph_softmax<<<dim3(N_, 2), 256, 0, stream>>>(fe, feKt, Acat8);
  k_xw_mfma<<<NROWS_/128, 256, 0, stream>>>(X, Wgcnt, HSb, Yt1, Yt2, Yt3);
  k_spatial_mfma<<<dim3(8, BT_/2), 256, 0, stream>>>(Acat8, Yt1, Yt2, Yt3, bgcn, HSb);
  k_qkv<<<NROWS_/128, 256, 0, stream>>>(X, STE, Wqkvt, bq, bk, bv, qb, kbuf, vbuf);
  k_attn_ht<<<(B_*N_)/4, 256, 0, stream>>>(qb, kbuf, vbuf, W1t, W2t, bx1, bx2, HTb);
  k_fusion_mfma<<<NROWS_/128, 256, 0, stream>>>(X, HSb, HTb, Wstt, Wh1t, Wh2t,
                                                btb, bh1, bh2, (float*)d_out);
}